// Round 1
// baseline (2843.057 us; speedup 1.0000x reference)
//
#include <hip/hip_runtime.h>
#include <hip/hip_bf16.h>
#include <math.h>

// ---------------------------------------------------------------------------
// CgpHmmCell forward: 512 sequences x 2048 steps x 25-state HMM.
// ws layout (floats): A[25*25] | I[25] | Bt[216*25]  (Bt[flat][state])
// ---------------------------------------------------------------------------

#define NSTATES 25
#define NFLAT   216
#define TLEN    2048
#define NSEQ    512
#define NEDGE   37

#define WS_A  0
#define WS_I  625
#define WS_BT 650

// Sparse structure of A (build_A): 37 nonzero (i,j) entries.
__device__ __constant__ int EDGE_I[NEDGE] = {
  0,0,1,2, 3,3,3,3, 4,5, 6,6,6, 7,8, 9,9, 10,11,12, 13,13, 14,15, 16,16,
  17,18, 19,19, 20,21, 22,22, 23,23, 24
};
__device__ __constant__ int EDGE_J[NEDGE] = {
  0,1,2,3, 4,14,7,10, 5,6, 7,17,10, 8,9, 20,10, 11,12,13, 13,23, 15,16, 4,14,
  18,19, 7,17, 21,22, 10,20, 23,24, 24
};

// Emission index spec (_emission_index_spec): 29 add-calls.
// Masks: bit c = symbol code c.  A=0x01 C=0x02 G=0x04 T=0x08 pad4=0x10 X=0x20
// N = 0x0F, N+4 = 0x1F, A+4 = 0x11, T+4 = 0x18, G+4 = 0x14.
struct BSpec { unsigned char st, m1, m2, m3, tr; };
__device__ __constant__ BSpec BSPECS[29] = {
  {0, 0x1F,0x1F,0x0F, 1},  // add(0,'N',0)
  {1, 0x1F,0x1F,0x01, 1},  // add(1,'A',0)
  {2, 0x1F,0x11,0x08, 1},  // add(2,'AT',0)
  {3, 0x11,0x18,0x04, 0},  // add(3,'ATG',0,False)
  {4, 0x18,0x14,0x0F, 1},  // add(4,'ATGN',0)
  {5, 0x14,0x1F,0x0F, 1},  // add(5,'ATGNN',0)
  {6, 0x1F,0x1F,0x0F, 1},  // add(6,'N',0)
  {7, 0x1F,0x1F,0x0F, 1},
  {8, 0x1F,0x1F,0x0F, 1},
  {9, 0x1F,0x1F,0x0F, 1},
  {10,0x0F,0x0F,0x08, 1},  // add(10,'T',2)
  {11,0x0F,0x08,0x01, 1},  // add(11,'TA',2)
  {11,0x0F,0x08,0x04, 1},  // add(11,'TG',2)
  {12,0x08,0x01,0x01, 0},  // add(12,'TAA',2,False)
  {12,0x08,0x01,0x04, 0},  // add(12,'TAG',2,False)
  {12,0x08,0x04,0x01, 0},  // add(12,'TGA',2,False)
  {13,0x0F,0x0F,0x0F, 1},  // add(13,'N',2)
  {14,0x1F,0x1F,0x0F, 1},  // add(14..22,'N',0)
  {15,0x1F,0x1F,0x0F, 1},
  {16,0x1F,0x1F,0x0F, 1},
  {17,0x1F,0x1F,0x0F, 1},
  {18,0x1F,0x1F,0x0F, 1},
  {19,0x1F,0x1F,0x0F, 1},
  {20,0x1F,0x1F,0x0F, 1},
  {21,0x1F,0x1F,0x0F, 1},
  {22,0x1F,0x1F,0x0F, 1},
  {23,0x0F,0x0F,0x20, 1},  // add(23,'X',2)
  {23,0x0F,0x20,0x20, 1},  // add(23,'XX',2)
  {24,0x20,0x20,0x20, 0},  // add(24,'XXX',2,False)
};

// ---------------------------------------------------------------------------
// Setup: build A (dense 25x25), I (25), Bt (216x25) into ws.
// ---------------------------------------------------------------------------
__global__ __launch_bounds__(256)
void setup_kernel(const float* __restrict__ wT, const float* __restrict__ wE,
                  const float* __restrict__ wI, float* __restrict__ ws) {
  __shared__ float slog[NSTATES * NFLAT];   // 21.6 KB emission logits
  __shared__ float alog[NSTATES * NSTATES]; // 2.5 KB transition logits
  const int tid = threadIdx.x;

  for (int i = tid; i < NSTATES * NFLAT; i += 256) slog[i] = -INFINITY;
  for (int i = tid; i < NSTATES * NSTATES; i += 256) alog[i] = -INFINITY;
  __syncthreads();

  if (tid == 0) {
    // ---- emission logits, k-order must match Python spec exactly ----
    int k = 0;
    for (int s = 0; s < 29; s++) {
      const BSpec sp = BSPECS[s];
      for (int c1 = 0; c1 < 6; c1++) {
        if (!((sp.m1 >> c1) & 1)) continue;
        for (int c2 = 0; c2 < 6; c2++) {
          if (!((sp.m2 >> c2) & 1)) continue;
          if (c1 != 4 && c2 == 4) continue;  // "4s only as prefix" filter (ORDER=2)
          for (int c3 = 0; c3 < 6; c3++) {
            if (!((sp.m3 >> c3) & 1)) continue;
            float v = sp.tr ? wE[k] : 1.0f;
            if (sp.tr) k++;
            slog[sp.st * NFLAT + c1 * 36 + c2 * 6 + c3] = v;
          }
        }
      }
    }
  } else if (tid == 64) {
    // ---- transition logits (build_A) ----
    const float w0 = wT[0], w1 = wT[1], w2 = wT[2], w3 = wT[3], w4 = wT[4];
    const float w5 = wT[5], w6 = wT[6], w7 = wT[7], w8 = wT[8], w9 = wT[9];
    #define SETA(i, j, v) alog[(i) * NSTATES + (j)] = (v)
    SETA(0, 0, 1.0f - w0); SETA(0, 1, w0);
    SETA(1, 2, 1.0f); SETA(2, 3, 1.0f);
    SETA(3, 4, w1); SETA(6, 7, w2);
    SETA(4, 5, 1.0f); SETA(7, 8, 1.0f);
    SETA(5, 6, 1.0f); SETA(8, 9, 1.0f);
    SETA(3, 14, w3); SETA(6, 17, w4); SETA(9, 20, w5);
    SETA(9, 10, 1.0f - w5);
    SETA(14, 15, 1.0f); SETA(17, 18, 1.0f); SETA(20, 21, 1.0f);
    SETA(15, 16, 1.0f); SETA(18, 19, 1.0f); SETA(21, 22, 1.0f);
    SETA(16, 4, w6); SETA(19, 7, w7); SETA(22, 10, w8);
    SETA(16, 14, 1.0f - w6); SETA(19, 17, 1.0f - w7); SETA(22, 20, 1.0f - w8);
    SETA(3, 7, 1.0f - w9 * w9); SETA(3, 10, 1.0f - w9 * w9 * w9);
    SETA(6, 10, 1.0f - w9 * w9);
    SETA(10, 11, 1.0f); SETA(11, 12, 1.0f); SETA(12, 13, 1.0f);
    SETA(13, 13, 1.0f); SETA(13, 23, 1.0f);
    SETA(23, 23, 1.0f); SETA(23, 24, 1.0f);
    SETA(24, 24, 1.0f);
    #undef SETA
  } else if (tid == 128) {
    // ---- I = softmax(wI[:9]) ----
    float e[9], s = 0.0f;
    for (int i = 0; i < 9; i++) { e[i] = expf(wI[i]); s += e[i]; }
    float inv = 1.0f / s;
    for (int i = 0; i < 9; i++) ws[WS_I + i] = e[i] * inv;
    for (int i = 9; i < NSTATES; i++) ws[WS_I + i] = 0.0f;
  }
  __syncthreads();

  if (tid < NSTATES) {
    // emission row softmax -> transposed Bt[flat][state]
    float sum = 0.0f;
    for (int c = 0; c < NFLAT; c++) {
      float v = slog[tid * NFLAT + c];
      if (v > -1e30f) sum += expf(v);
    }
    float inv = 1.0f / sum;
    for (int c = 0; c < NFLAT; c++) {
      float v = slog[tid * NFLAT + c];
      ws[WS_BT + c * NSTATES + tid] = (v > -1e30f) ? expf(v) * inv : 0.0f;
    }
    // transition row softmax -> dense A
    float asum = 0.0f;
    for (int j = 0; j < NSTATES; j++) {
      float v = alog[tid * NSTATES + j];
      if (v > -1e30f) asum += expf(v);
    }
    float ainv = 1.0f / asum;
    for (int j = 0; j < NSTATES; j++) {
      float v = alog[tid * NSTATES + j];
      ws[WS_A + tid * NSTATES + j] = (v > -1e30f) ? expf(v) * ainv : 0.0f;
    }
  }
}

// ---------------------------------------------------------------------------
// Forward scan: one thread per sequence, alpha[25] in registers,
// sparse-A matvec (37 FMA), renormalize every 8 steps.
// ---------------------------------------------------------------------------
__device__ __forceinline__ void hmm_step(float (&alpha)[NSTATES],
                                         const float (&Av)[NEDGE],
                                         const float* __restrict__ sBt,
                                         int flat) {
  float na[NSTATES];
  #pragma unroll
  for (int j = 0; j < NSTATES; j++) na[j] = 0.0f;
  #pragma unroll
  for (int e = 0; e < NEDGE; e++) na[EDGE_J[e]] += alpha[EDGE_I[e]] * Av[e];
  const float* er = sBt + flat * NSTATES;
  #pragma unroll
  for (int j = 0; j < NSTATES; j++) alpha[j] = na[j] * er[j];
}

__device__ __forceinline__ void renorm(float (&alpha)[NSTATES], float& ll) {
  float s = 0.0f;
  #pragma unroll
  for (int j = 0; j < NSTATES; j++) s += alpha[j];
  ll += __logf(s);
  float r = __fdividef(1.0f, s);
  #pragma unroll
  for (int j = 0; j < NSTATES; j++) alpha[j] *= r;
}

__global__ __launch_bounds__(64)
void fwd_kernel(const float* __restrict__ ws, const int* __restrict__ tokens,
                float* __restrict__ out) {
  __shared__ float sBt[NFLAT * NSTATES];
  for (int i = threadIdx.x; i < NFLAT * NSTATES; i += 64) sBt[i] = ws[WS_BT + i];
  __syncthreads();

  const int seq = blockIdx.x * 64 + threadIdx.x;
  const int* trow = tokens + (size_t)seq * TLEN;

  float Av[NEDGE];
  #pragma unroll
  for (int e = 0; e < NEDGE; e++) Av[e] = ws[WS_A + EDGE_I[e] * NSTATES + EDGE_J[e]];

  // tokens for chunk 0
  int4 a0 = *(const int4*)(trow);
  int4 a1 = *(const int4*)(trow + 4);
  int tb[8] = {a0.x, a0.y, a0.z, a0.w, a1.x, a1.y, a1.z, a1.w};

  // t = 0: flat = 4*36 + 4*6 + tok0 = 168 + tok0
  float alpha[NSTATES];
  {
    int flat = 168 + tb[0];
    const float* er = sBt + flat * NSTATES;
    #pragma unroll
    for (int j = 0; j < NSTATES; j++) alpha[j] = ws[WS_I + j] * er[j];
  }
  float ll = 0.0f;
  int p1 = 4, p2 = tb[0];

  // prefetch chunk 1 tokens
  int4 n0 = *(const int4*)(trow + 8);
  int4 n1 = *(const int4*)(trow + 12);

  // chunk 0: steps t = 1..7
  #pragma unroll
  for (int u = 1; u < 8; u++) {
    int nt = tb[u];
    int flat = p1 * 36 + p2 * 6 + nt;
    hmm_step(alpha, Av, sBt, flat);
    p1 = p2; p2 = nt;
  }
  renorm(alpha, ll);

  for (int c = 1; c < TLEN / 8; c++) {
    tb[0] = n0.x; tb[1] = n0.y; tb[2] = n0.z; tb[3] = n0.w;
    tb[4] = n1.x; tb[5] = n1.y; tb[6] = n1.z; tb[7] = n1.w;
    if (c < TLEN / 8 - 1) {
      n0 = *(const int4*)(trow + (c + 1) * 8);
      n1 = *(const int4*)(trow + (c + 1) * 8 + 4);
    }
    #pragma unroll
    for (int u = 0; u < 8; u++) {
      int nt = tb[u];
      int flat = p1 * 36 + p2 * 6 + nt;
      hmm_step(alpha, Av, sBt, flat);
      p1 = p2; p2 = nt;
    }
    renorm(alpha, ll);
  }

  out[seq] = ll;
}

// ---------------------------------------------------------------------------
extern "C" void kernel_launch(void* const* d_in, const int* in_sizes, int n_in,
                              void* d_out, int out_size, void* d_ws, size_t ws_size,
                              hipStream_t stream) {
  const float* wT = (const float*)d_in[0];   // transition_kernel (10)
  const float* wE = (const float*)d_in[1];   // emission_kernel (5400)
  const float* wI = (const float*)d_in[2];   // init_kernel (25)
  const int* tokens = (const int*)d_in[3];   // (512, 2048) int32
  float* out = (float*)d_out;                // (512,) float32
  float* ws = (float*)d_ws;                  // >= 6050 floats

  setup_kernel<<<1, 256, 0, stream>>>(wT, wE, wI, ws);
  fwd_kernel<<<NSEQ / 64, 64, 0, stream>>>(ws, tokens, out);
}

// Round 2
// 286.740 us; speedup vs baseline: 9.9151x; 9.9151x over previous
//
#include <hip/hip_runtime.h>
#include <hip/hip_bf16.h>
#include <math.h>

// ---------------------------------------------------------------------------
// CgpHmmCell forward: 512 seqs x 2048 steps x 25-state HMM.
// Strategy: per (seq, chunk-of-256-steps), propagate all 25 basis rows in
// parallel (lane-per-row) -> 25x25 chunk transfer matrices with per-row log
// scales; then per-seq combine of the 8 chunk matrices.
//
// ws layout (floats):
//   WS_AW = 0    : 21 packed softmaxed A-weights (multi-entry rows only)
//   WS_I  = 32   : 25 init probs
//   WS_BT = 64   : Bt[216][32]  (emission row per flat, pitch 32, states 0..24)
//   WS_T  = 6976 : T[512][8][25][32]  (row 0..24 values at [0..24], L at [25])
// ---------------------------------------------------------------------------

#define NSTATES 25
#define NFLAT   216
#define TLEN    2048
#define NSEQ    512
#define CHUNKS  8
#define CLEN    256   // steps per chunk (chunk 0: 255, skips t=0)

#define WS_AW 0
#define WS_I  32
#define WS_BT 64
#define WS_T  6976    // byte offset 27904, 16B aligned

// Emission index spec (_emission_index_spec): 29 add-calls (validated round 1).
// bit c = symbol code c.  A=0x01 C=0x02 G=0x04 T=0x08 pad4=0x10 X=0x20
struct BSpec { unsigned char st, m1, m2, m3, tr; };
__device__ __constant__ BSpec BSPECS[29] = {
  {0, 0x1F,0x1F,0x0F, 1},  {1, 0x1F,0x1F,0x01, 1},  {2, 0x1F,0x11,0x08, 1},
  {3, 0x11,0x18,0x04, 0},  {4, 0x18,0x14,0x0F, 1},  {5, 0x14,0x1F,0x0F, 1},
  {6, 0x1F,0x1F,0x0F, 1},  {7, 0x1F,0x1F,0x0F, 1},  {8, 0x1F,0x1F,0x0F, 1},
  {9, 0x1F,0x1F,0x0F, 1},  {10,0x0F,0x0F,0x08, 1},  {11,0x0F,0x08,0x01, 1},
  {11,0x0F,0x08,0x04, 1},  {12,0x08,0x01,0x01, 0},  {12,0x08,0x01,0x04, 0},
  {12,0x08,0x04,0x01, 0},  {13,0x0F,0x0F,0x0F, 1},  {14,0x1F,0x1F,0x0F, 1},
  {15,0x1F,0x1F,0x0F, 1},  {16,0x1F,0x1F,0x0F, 1},  {17,0x1F,0x1F,0x0F, 1},
  {18,0x1F,0x1F,0x0F, 1},  {19,0x1F,0x1F,0x0F, 1},  {20,0x1F,0x1F,0x0F, 1},
  {21,0x1F,0x1F,0x0F, 1},  {22,0x1F,0x1F,0x0F, 1},  {23,0x0F,0x0F,0x20, 1},
  {23,0x0F,0x20,0x20, 1},  {24,0x20,0x20,0x20, 0},
};

// ---------------------------------------------------------------------------
// Setup: packed A-weights (21), I (25), Bt (216x32) into ws.
// Single-entry softmax rows of A are exactly 1.0 -> hardcoded in the step.
// ---------------------------------------------------------------------------
__global__ __launch_bounds__(256)
void setup_kernel(const float* __restrict__ wT, const float* __restrict__ wE,
                  const float* __restrict__ wI, float* __restrict__ ws) {
  __shared__ float slog[NSTATES * NFLAT];   // 21.6 KB emission logits
  const int tid = threadIdx.x;

  for (int i = tid; i < NSTATES * NFLAT; i += 256) slog[i] = -INFINITY;
  __syncthreads();

  if (tid == 0) {
    // emission logits, k-order must match Python spec exactly
    int k = 0;
    for (int s = 0; s < 29; s++) {
      const BSpec sp = BSPECS[s];
      for (int c1 = 0; c1 < 6; c1++) {
        if (!((sp.m1 >> c1) & 1)) continue;
        for (int c2 = 0; c2 < 6; c2++) {
          if (!((sp.m2 >> c2) & 1)) continue;
          if (c1 != 4 && c2 == 4) continue;  // pad-4 only as prefix (ORDER=2)
          for (int c3 = 0; c3 < 6; c3++) {
            if (!((sp.m3 >> c3) & 1)) continue;
            float v = sp.tr ? wE[k] : 1.0f;
            if (sp.tr) k++;
            slog[sp.st * NFLAT + c1 * 36 + c2 * 6 + c3] = v;
          }
        }
      }
    }
  } else if (tid == 64) {
    // softmax of multi-entry A rows -> 21 packed weights
    const float w0 = wT[0], w1 = wT[1], w2 = wT[2], w3 = wT[3], w4 = wT[4];
    const float w5 = wT[5], w6 = wT[6], w7 = wT[7], w8 = wT[8], w9 = wT[9];
    // row 0: (0,0)=1-w0, (0,1)=w0
    {
      float e0 = expf(1.0f - w0), e1 = expf(w0), is = 1.0f / (e0 + e1);
      ws[WS_AW + 0] = e0 * is; ws[WS_AW + 1] = e1 * is;
    }
    // row 3: (3,4)=w1, (3,14)=w3, (3,7)=1-w9^2, (3,10)=1-w9^3
    {
      float e4 = expf(w1), e14 = expf(w3);
      float e7 = expf(1.0f - w9 * w9), e10 = expf(1.0f - w9 * w9 * w9);
      float is = 1.0f / (e4 + e14 + e7 + e10);
      ws[WS_AW + 2] = e4 * is;  ws[WS_AW + 3] = e14 * is;
      ws[WS_AW + 4] = e7 * is;  ws[WS_AW + 5] = e10 * is;
    }
    // row 6: (6,7)=w2, (6,17)=w4, (6,10)=1-w9^2
    {
      float e7 = expf(w2), e17 = expf(w4), e10 = expf(1.0f - w9 * w9);
      float is = 1.0f / (e7 + e17 + e10);
      ws[WS_AW + 6] = e7 * is; ws[WS_AW + 7] = e17 * is; ws[WS_AW + 8] = e10 * is;
    }
    // row 9: (9,20)=w5, (9,10)=1-w5
    {
      float e20 = expf(w5), e10 = expf(1.0f - w5), is = 1.0f / (e20 + e10);
      ws[WS_AW + 9] = e20 * is; ws[WS_AW + 10] = e10 * is;
    }
    // row 13: (13,13)=1, (13,23)=1 -> 0.5/0.5
    ws[WS_AW + 11] = 0.5f; ws[WS_AW + 12] = 0.5f;
    // row 16: (16,4)=w6, (16,14)=1-w6
    {
      float e4 = expf(w6), e14 = expf(1.0f - w6), is = 1.0f / (e4 + e14);
      ws[WS_AW + 13] = e4 * is; ws[WS_AW + 14] = e14 * is;
    }
    // row 19: (19,7)=w7, (19,17)=1-w7
    {
      float e7 = expf(w7), e17 = expf(1.0f - w7), is = 1.0f / (e7 + e17);
      ws[WS_AW + 15] = e7 * is; ws[WS_AW + 16] = e17 * is;
    }
    // row 22: (22,10)=w8, (22,20)=1-w8
    {
      float e10 = expf(w8), e20 = expf(1.0f - w8), is = 1.0f / (e10 + e20);
      ws[WS_AW + 17] = e10 * is; ws[WS_AW + 18] = e20 * is;
    }
    // row 23: (23,23)=1, (23,24)=1 -> 0.5/0.5
    ws[WS_AW + 19] = 0.5f; ws[WS_AW + 20] = 0.5f;
  } else if (tid == 128) {
    // I = softmax(wI[:9])
    float e[9], s = 0.0f;
    for (int i = 0; i < 9; i++) { e[i] = expf(wI[i]); s += e[i]; }
    float inv = 1.0f / s;
    for (int i = 0; i < 9; i++) ws[WS_I + i] = e[i] * inv;
    for (int i = 9; i < NSTATES; i++) ws[WS_I + i] = 0.0f;
  }
  __syncthreads();

  if (tid < NSTATES) {
    // emission row softmax -> transposed Bt[flat][state], pitch 32
    float sum = 0.0f;
    for (int c = 0; c < NFLAT; c++) {
      float v = slog[tid * NFLAT + c];
      if (v > -1e30f) sum += expf(v);
    }
    float inv = 1.0f / sum;
    for (int c = 0; c < NFLAT; c++) {
      float v = slog[tid * NFLAT + c];
      ws[WS_BT + c * 32 + tid] = (v > -1e30f) ? expf(v) * inv : 0.0f;
    }
  }
}

// ---------------------------------------------------------------------------
// One HMM step: sparse matvec with 21 weighted edges (SGPR) + 16 hardwired
// weight-1.0 pass-throughs, then elementwise emission multiply (LDS b128
// broadcast reads: flat is uniform within the 32-lane group).
// ---------------------------------------------------------------------------
__device__ __forceinline__ void hmm_step(float (&a)[25], const float (&w)[21],
                                         const float* __restrict__ bt, int flat) {
  const float* er = bt + (flat << 5);
  float4 e0 = *(const float4*)(er + 0);
  float4 e1 = *(const float4*)(er + 4);
  float4 e2 = *(const float4*)(er + 8);
  float4 e3 = *(const float4*)(er + 12);
  float4 e4 = *(const float4*)(er + 16);
  float4 e5 = *(const float4*)(er + 20);
  float  e24 = er[24];

  float n0  = a[0]*w[0];
  float n1  = a[0]*w[1];
  float n4  = a[3]*w[2]  + a[16]*w[13];
  float n7  = a[3]*w[4]  + a[6]*w[6]  + a[19]*w[15];
  float n10 = a[3]*w[5]  + a[6]*w[8]  + a[9]*w[10] + a[22]*w[17];
  float n13 = a[12]      + a[13]*w[11];
  float n14 = a[3]*w[3]  + a[16]*w[14];
  float n17 = a[6]*w[7]  + a[19]*w[16];
  float n20 = a[9]*w[9]  + a[22]*w[18];
  float n23 = a[13]*w[12] + a[23]*w[19];
  float n24 = a[23]*w[20] + a[24];
  float o2 = a[1],  o3 = a[2],  o5 = a[4],  o6 = a[5];
  float o8 = a[7],  o9 = a[8],  o11 = a[10], o12 = a[11];
  float o15 = a[14], o16 = a[15], o18 = a[17], o19 = a[18];
  float o21 = a[20], o22 = a[21];

  a[0] = n0 * e0.x;  a[1] = n1 * e0.y;  a[2] = o2 * e0.z;  a[3] = o3 * e0.w;
  a[4] = n4 * e1.x;  a[5] = o5 * e1.y;  a[6] = o6 * e1.z;  a[7] = n7 * e1.w;
  a[8] = o8 * e2.x;  a[9] = o9 * e2.y;  a[10] = n10 * e2.z; a[11] = o11 * e2.w;
  a[12] = o12 * e3.x; a[13] = n13 * e3.y; a[14] = n14 * e3.z; a[15] = o15 * e3.w;
  a[16] = o16 * e4.x; a[17] = n17 * e4.y; a[18] = o18 * e4.z; a[19] = o19 * e4.w;
  a[20] = n20 * e5.x; a[21] = o21 * e5.y; a[22] = o22 * e5.z; a[23] = n23 * e5.w;
  a[24] = n24 * e24;
}

__device__ __forceinline__ void renorm(float (&a)[25], float& L) {
  float s = (((a[0]+a[1])+(a[2]+a[3])) + ((a[4]+a[5])+(a[6]+a[7])))
          + (((a[8]+a[9])+(a[10]+a[11])) + ((a[12]+a[13])+(a[14]+a[15])))
          + (((a[16]+a[17])+(a[18]+a[19])) + ((a[20]+a[21])+(a[22]+a[23])))
          + a[24];
  if (s > 0.0f) {
    L += __logf(s);
    float r = __fdividef(1.0f, s);
    #pragma unroll
    for (int j = 0; j < 25; j++) a[j] *= r;
  } else {
    L = -3.0e38f;  // row died (structural zero emissions); stays dead
  }
}

// ---------------------------------------------------------------------------
// Main kernel: 32-lane group = one (seq, chunk); lane = basis row.
// grid 512 blocks x 256 threads = 512 seqs x 8 chunks x 32 lanes.
// ---------------------------------------------------------------------------
__global__ __launch_bounds__(256)
void rows_kernel(const float* __restrict__ ws, const int* __restrict__ tokens,
                 float* __restrict__ wsT) {
  __shared__ float sBt[NFLAT * 32];   // 27.6 KB
  for (int i = threadIdx.x; i < NFLAT * 32; i += 256) sBt[i] = ws[WS_BT + i];
  __syncthreads();

  const int g     = blockIdx.x * 8 + (threadIdx.x >> 5);
  const int seq   = g >> 3;
  const int chunk = g & 7;
  const int row   = threadIdx.x & 31;
  const int* trow = tokens + (size_t)seq * TLEN;
  const int t0    = chunk * CLEN;

  float w[21];
  #pragma unroll
  for (int i = 0; i < 21; i++) w[i] = ws[WS_AW + i];  // uniform -> SGPRs

  float a[25];
  #pragma unroll
  for (int j = 0; j < 25; j++) a[j] = 0.0f;
  if (row < 25) a[row] = 1.0f;
  float L = 0.0f;

  int p1, p2;
  int4 q0 = *(const int4*)(trow + t0);
  int4 q1 = *(const int4*)(trow + t0 + 4);

  int b = 0;
  if (chunk == 0) {
    // steps t = 1..7 (t = 0 is folded into the combine's init)
    p1 = 4; p2 = q0.x;
    int tb[8] = {q0.x, q0.y, q0.z, q0.w, q1.x, q1.y, q1.z, q1.w};
    q0 = *(const int4*)(trow + 8);
    q1 = *(const int4*)(trow + 12);
    #pragma unroll
    for (int u = 1; u < 8; u++) {
      int nt = tb[u];
      hmm_step(a, w, sBt, p1 * 36 + p2 * 6 + nt);
      p1 = p2; p2 = nt;
    }
    renorm(a, L);
    b = 1;
  } else {
    p1 = trow[t0 - 2];
    p2 = trow[t0 - 1];
  }

  for (; b < CLEN / 8; b++) {
    int tb[8] = {q0.x, q0.y, q0.z, q0.w, q1.x, q1.y, q1.z, q1.w};
    if (b < CLEN / 8 - 1) {
      q0 = *(const int4*)(trow + t0 + (b + 1) * 8);
      q1 = *(const int4*)(trow + t0 + (b + 1) * 8 + 4);
    }
    #pragma unroll
    for (int u = 0; u < 8; u++) {
      int nt = tb[u];
      hmm_step(a, w, sBt, p1 * 36 + p2 * 6 + nt);
      p1 = p2; p2 = nt;
    }
    renorm(a, L);
  }

  // store normalized row + log-scale
  if (row < 25) {
    float* tb_ = wsT + WS_T + (size_t)((seq * CHUNKS + chunk) * 25 + row) * 32;
    *(float4*)(tb_ + 0)  = make_float4(a[0],  a[1],  a[2],  a[3]);
    *(float4*)(tb_ + 4)  = make_float4(a[4],  a[5],  a[6],  a[7]);
    *(float4*)(tb_ + 8)  = make_float4(a[8],  a[9],  a[10], a[11]);
    *(float4*)(tb_ + 12) = make_float4(a[12], a[13], a[14], a[15]);
    *(float4*)(tb_ + 16) = make_float4(a[16], a[17], a[18], a[19]);
    *(float4*)(tb_ + 20) = make_float4(a[20], a[21], a[22], a[23]);
    tb_[24] = a[24];
    tb_[25] = L;
  }
}

// ---------------------------------------------------------------------------
// Combine: one wave per sequence; lane j owns state-column j.
// v' = sum_r v_r * exp(L_r - m) * T_c[r][:], renormalize, accumulate ll.
// ---------------------------------------------------------------------------
__global__ __launch_bounds__(256)
void combine_kernel(const float* __restrict__ ws, const int* __restrict__ tokens,
                    float* __restrict__ out) {
  const int wave = (blockIdx.x * 256 + threadIdx.x) >> 6;  // = seq
  const int lane = threadIdx.x & 63;
  const int j    = lane;
  const bool act = (j < 25);
  const int jc   = act ? j : 0;  // clamped address for inactive lanes

  const int tok0 = tokens[(size_t)wave * TLEN];
  const int flat0 = 168 + tok0;  // tp context (4,4,tok0)

  float v = act ? ws[WS_I + j] * ws[WS_BT + flat0 * 32 + j] : 0.0f;
  float s = v;
  #pragma unroll
  for (int m = 1; m < 32; m <<= 1) s += __shfl_xor(s, m, 32);
  float ll = __logf(s);
  v = act ? v * __fdividef(1.0f, s) : 0.0f;

  const float* T = ws + WS_T + (size_t)wave * CHUNKS * 25 * 32;
  for (int c = 0; c < CHUNKS; c++) {
    const float* Tc = T + c * 25 * 32;
    float Lj  = act ? Tc[j * 32 + 25] : -3.0e38f;
    float key = (act && v > 0.0f) ? Lj : -3.0e38f;
    float mx = key;
    #pragma unroll
    for (int m = 1; m < 32; m <<= 1) mx = fmaxf(mx, __shfl_xor(mx, m, 32));
    float wgt = (act && v > 0.0f) ? v * __expf(Lj - mx) : 0.0f;

    float nv = 0.0f;
    #pragma unroll
    for (int r = 0; r < 25; r++) {
      float wr = __shfl(wgt, r, 64);
      nv += wr * Tc[r * 32 + jc];
    }
    float nva = act ? nv : 0.0f;
    float s2 = nva;
    #pragma unroll
    for (int m = 1; m < 32; m <<= 1) s2 += __shfl_xor(s2, m, 32);
    ll += mx + __logf(s2);
    v = act ? nv * __fdividef(1.0f, s2) : 0.0f;
  }

  if (lane == 0) out[wave] = ll;
}

// ---------------------------------------------------------------------------
extern "C" void kernel_launch(void* const* d_in, const int* in_sizes, int n_in,
                              void* d_out, int out_size, void* d_ws, size_t ws_size,
                              hipStream_t stream) {
  const float* wT = (const float*)d_in[0];   // transition_kernel (10)
  const float* wE = (const float*)d_in[1];   // emission_kernel (5400)
  const float* wI = (const float*)d_in[2];   // init_kernel (25)
  const int* tokens = (const int*)d_in[3];   // (512, 2048) int32
  float* out = (float*)d_out;                // (512,) float32
  float* ws = (float*)d_ws;                  // needs ~13.2 MB

  setup_kernel<<<1, 256, 0, stream>>>(wT, wE, wI, ws);
  rows_kernel<<<NSEQ, 256, 0, stream>>>(ws, tokens, ws);
  combine_kernel<<<NSEQ * 64 / 256, 256, 0, stream>>>(ws, tokens, out);
}

// Round 3
// 167.463 us; speedup vs baseline: 16.9772x; 1.7123x over previous
//
#include <hip/hip_runtime.h>
#include <hip/hip_bf16.h>
#include <math.h>

// ---------------------------------------------------------------------------
// CgpHmmCell forward: 512 seqs x 2048 steps x 25-state HMM.
// States 23/24 emit only 'X' (never present in tokens in [0,4)) -> always 0
// after the emission multiply; dropped everywhere (23 live states).
//
// Per (seq, chunk-of-128-steps): propagate 23 basis rows in parallel
// (lane-per-row, 32-lane group) -> 23x23 chunk transfer matrix + per-row log
// scale; then per-seq combine of the 16 chunk matrices.
//
// ws layout (floats):
//   WS_AW = 0    : 21 packed softmaxed A-weights (multi-entry rows only)
//   WS_I  = 32   : init probs (32, states 9.. zero)
//   WS_BT = 64   : Bt[216][32] (emission row per flat, pitch 32, states 0..24)
//   WS_T  = 6976 : T[512][16][23][24]  (a0..a22 at [0..22], L at [23])
//                  -> total 4,528,960 floats = 18.1 MB
// ---------------------------------------------------------------------------

#define NSTATES 25
#define NLIVE   23
#define NFLAT   216
#define TLEN    2048
#define NSEQ    512
#define CHUNKS  16
#define CLEN    128

#define WS_AW 0
#define WS_I  32
#define WS_BT 64
#define WS_T  6976

// ---------------------------------------------------------------------------
// Compile-time emission map: WMAP[state*216+flat] = k-index into wE,
// -1 = non-trainable (logit 1.0), -2 = absent (-inf).
// Spec identical to the round-1-validated enumeration (absmax was 0.0).
// ---------------------------------------------------------------------------
struct WMap { short m[NSTATES * NFLAT]; };

constexpr WMap make_wmap() {
  WMap w{};
  for (int i = 0; i < NSTATES * NFLAT; i++) w.m[i] = -2;
  // bit c = symbol code c. A=0x01 C=0x02 G=0x04 T=0x08 pad4=0x10 X=0x20
  const unsigned char ST[29] = {0,1,2,3,4,5,6,7,8,9,10,11,11,12,12,12,13,
                                14,15,16,17,18,19,20,21,22,23,23,24};
  const unsigned char M1[29] = {0x1F,0x1F,0x1F,0x11,0x18,0x14,0x1F,0x1F,0x1F,
                                0x1F,0x0F,0x0F,0x0F,0x08,0x08,0x08,0x0F,
                                0x1F,0x1F,0x1F,0x1F,0x1F,0x1F,0x1F,0x1F,0x1F,
                                0x0F,0x0F,0x20};
  const unsigned char M2[29] = {0x1F,0x1F,0x11,0x18,0x14,0x1F,0x1F,0x1F,0x1F,
                                0x1F,0x0F,0x08,0x08,0x01,0x01,0x04,0x0F,
                                0x1F,0x1F,0x1F,0x1F,0x1F,0x1F,0x1F,0x1F,0x1F,
                                0x0F,0x20,0x20};
  const unsigned char M3[29] = {0x0F,0x01,0x08,0x04,0x0F,0x0F,0x0F,0x0F,0x0F,
                                0x0F,0x08,0x01,0x04,0x01,0x04,0x01,0x0F,
                                0x0F,0x0F,0x0F,0x0F,0x0F,0x0F,0x0F,0x0F,0x0F,
                                0x20,0x20,0x20};
  const unsigned char TR[29] = {1,1,1,0,1,1,1,1,1,1,1,1,1,0,0,0,1,
                                1,1,1,1,1,1,1,1,1,1,1,0};
  int k = 0;
  for (int s = 0; s < 29; s++) {
    for (int c1 = 0; c1 < 6; c1++) {
      if (!((M1[s] >> c1) & 1)) continue;
      for (int c2 = 0; c2 < 6; c2++) {
        if (!((M2[s] >> c2) & 1)) continue;
        if (c1 != 4 && c2 == 4) continue;  // pad-4 only as prefix (ORDER=2)
        for (int c3 = 0; c3 < 6; c3++) {
          if (!((M3[s] >> c3) & 1)) continue;
          w.m[ST[s] * NFLAT + c1 * 36 + c2 * 6 + c3] =
              TR[s] ? (short)(k++) : (short)-1;
        }
      }
    }
  }
  return w;
}
__device__ __constant__ WMap WMAP = make_wmap();

// ---------------------------------------------------------------------------
// Setup (fully parallel): Bt[216][32], 21 A-weights, I.
// ---------------------------------------------------------------------------
__global__ __launch_bounds__(256)
void setup_kernel(const float* __restrict__ wT, const float* __restrict__ wE,
                  const float* __restrict__ wI, float* __restrict__ ws) {
  __shared__ float sE[NSTATES * NFLAT];   // exp(logit), 0 where absent
  __shared__ float sPart[25 * 8];
  __shared__ float sInv[25];
  const int tid = threadIdx.x;

  for (int i = tid; i < NSTATES * NFLAT; i += 256) {
    short m = WMAP.m[i];
    float e = 0.0f;
    if (m == -1) e = expf(1.0f);
    else if (m >= 0) e = expf(wE[m]);
    sE[i] = e;
  }
  __syncthreads();

  if (tid < 200) {               // 25 rows x 8 partials of 27
    int row = tid >> 3, part = tid & 7;
    float s = 0.0f;
    const float* r = sE + row * NFLAT + part * 27;
    for (int c = 0; c < 27; c++) s += r[c];
    sPart[tid] = s;
  } else if (tid == 254) {
    // softmax of multi-entry A rows -> 21 packed weights
    const float w0 = wT[0], w1 = wT[1], w2 = wT[2], w3 = wT[3], w4 = wT[4];
    const float w5 = wT[5], w6 = wT[6], w7 = wT[7], w8 = wT[8], w9 = wT[9];
    { float e0 = expf(1.0f - w0), e1 = expf(w0), is = 1.0f / (e0 + e1);
      ws[WS_AW + 0] = e0 * is; ws[WS_AW + 1] = e1 * is; }
    { float e4 = expf(w1), e14 = expf(w3);
      float e7 = expf(1.0f - w9 * w9), e10 = expf(1.0f - w9 * w9 * w9);
      float is = 1.0f / (e4 + e14 + e7 + e10);
      ws[WS_AW + 2] = e4 * is;  ws[WS_AW + 3] = e14 * is;
      ws[WS_AW + 4] = e7 * is;  ws[WS_AW + 5] = e10 * is; }
    { float e7 = expf(w2), e17 = expf(w4), e10 = expf(1.0f - w9 * w9);
      float is = 1.0f / (e7 + e17 + e10);
      ws[WS_AW + 6] = e7 * is; ws[WS_AW + 7] = e17 * is; ws[WS_AW + 8] = e10 * is; }
    { float e20 = expf(w5), e10 = expf(1.0f - w5), is = 1.0f / (e20 + e10);
      ws[WS_AW + 9] = e20 * is; ws[WS_AW + 10] = e10 * is; }
    ws[WS_AW + 11] = 0.5f; ws[WS_AW + 12] = 0.5f;   // row 13
    { float e4 = expf(w6), e14 = expf(1.0f - w6), is = 1.0f / (e4 + e14);
      ws[WS_AW + 13] = e4 * is; ws[WS_AW + 14] = e14 * is; }
    { float e7 = expf(w7), e17 = expf(1.0f - w7), is = 1.0f / (e7 + e17);
      ws[WS_AW + 15] = e7 * is; ws[WS_AW + 16] = e17 * is; }
    { float e10 = expf(w8), e20 = expf(1.0f - w8), is = 1.0f / (e10 + e20);
      ws[WS_AW + 17] = e10 * is; ws[WS_AW + 18] = e20 * is; }
    ws[WS_AW + 19] = 0.5f; ws[WS_AW + 20] = 0.5f;   // row 23 (unused)
  } else if (tid == 255) {
    float e[9], s = 0.0f;
    for (int i = 0; i < 9; i++) { e[i] = expf(wI[i]); s += e[i]; }
    float inv = 1.0f / s;
    for (int i = 0; i < 9; i++) ws[WS_I + i] = e[i] * inv;
    for (int i = 9; i < 32; i++) ws[WS_I + i] = 0.0f;
  }
  __syncthreads();

  if (tid < 25) {
    float s = 0.0f;
    #pragma unroll
    for (int p = 0; p < 8; p++) s += sPart[tid * 8 + p];
    sInv[tid] = 1.0f / s;
  }
  __syncthreads();

  for (int i = tid; i < NFLAT * 32; i += 256) {
    int st = i & 31, c = i >> 5;
    ws[WS_BT + i] = (st < 25) ? sE[st * NFLAT + c] * sInv[st] : 0.0f;
  }
}

// ---------------------------------------------------------------------------
// One HMM step over the 23 live states: 21 weighted edges + 14 weight-1.0
// pass-throughs, then emission multiply (LDS b128 broadcast reads; flat is
// uniform within the 32-lane group).
// ---------------------------------------------------------------------------
__device__ __forceinline__ void hmm_step(float (&a)[NLIVE], const float (&w)[21],
                                         const float* __restrict__ bt, int flat) {
  const float* er = bt + (flat << 5);
  float4 e0 = *(const float4*)(er + 0);
  float4 e1 = *(const float4*)(er + 4);
  float4 e2 = *(const float4*)(er + 8);
  float4 e3 = *(const float4*)(er + 12);
  float4 e4 = *(const float4*)(er + 16);
  float4 e5 = *(const float4*)(er + 20);   // .w = state 23, unused

  float n0  = a[0]*w[0];
  float n1  = a[0]*w[1];
  float n4  = a[3]*w[2]  + a[16]*w[13];
  float n7  = a[3]*w[4]  + a[6]*w[6]  + a[19]*w[15];
  float n10 = a[3]*w[5]  + a[6]*w[8]  + a[9]*w[10] + a[22]*w[17];
  float n13 = a[12]      + a[13]*w[11];
  float n14 = a[3]*w[3]  + a[16]*w[14];
  float n17 = a[6]*w[7]  + a[19]*w[16];
  float n20 = a[9]*w[9]  + a[22]*w[18];
  float o2 = a[1],  o3 = a[2],  o5 = a[4],  o6 = a[5];
  float o8 = a[7],  o9 = a[8],  o11 = a[10], o12 = a[11];
  float o15 = a[14], o16 = a[15], o18 = a[17], o19 = a[18];
  float o21 = a[20], o22 = a[21];

  a[0] = n0 * e0.x;  a[1] = n1 * e0.y;  a[2] = o2 * e0.z;  a[3] = o3 * e0.w;
  a[4] = n4 * e1.x;  a[5] = o5 * e1.y;  a[6] = o6 * e1.z;  a[7] = n7 * e1.w;
  a[8] = o8 * e2.x;  a[9] = o9 * e2.y;  a[10] = n10 * e2.z; a[11] = o11 * e2.w;
  a[12] = o12 * e3.x; a[13] = n13 * e3.y; a[14] = n14 * e3.z; a[15] = o15 * e3.w;
  a[16] = o16 * e4.x; a[17] = n17 * e4.y; a[18] = o18 * e4.z; a[19] = o19 * e4.w;
  a[20] = n20 * e5.x; a[21] = o21 * e5.y; a[22] = o22 * e5.z;
}

__device__ __forceinline__ void renorm(float (&a)[NLIVE], float& L) {
  float s = (((a[0]+a[1])+(a[2]+a[3])) + ((a[4]+a[5])+(a[6]+a[7])))
          + (((a[8]+a[9])+(a[10]+a[11])) + ((a[12]+a[13])+(a[14]+a[15])))
          + (((a[16]+a[17])+(a[18]+a[19])) + ((a[20]+a[21])+a[22]));
  if (s > 0.0f) {
    L += __logf(s);
    float r = __fdividef(1.0f, s);
    #pragma unroll
    for (int j = 0; j < NLIVE; j++) a[j] *= r;
  } else {
    L = -3.0e38f;  // row died (restricted-emission state path); stays dead
  }
}

// ---------------------------------------------------------------------------
// rows: 32-lane group = one (seq, chunk); lane = basis row (0..22 live).
// grid 1024 blocks x 256 threads = 512 seqs x 16 chunks x 32 lanes.
// ---------------------------------------------------------------------------
__global__ __launch_bounds__(256)
void rows_kernel(const float* __restrict__ ws, const int* __restrict__ tokens,
                 float* __restrict__ wsT) {
  __shared__ float sBt[NFLAT * 32];   // 27.6 KB
  for (int i = threadIdx.x; i < NFLAT * 32; i += 256) sBt[i] = ws[WS_BT + i];
  __syncthreads();

  const int g     = blockIdx.x * 8 + (threadIdx.x >> 5);
  const int seq   = g >> 4;
  const int chunk = g & 15;
  const int row   = threadIdx.x & 31;
  const int* trow = tokens + (size_t)seq * TLEN;
  const int t0    = chunk * CLEN;

  float w[21];
  #pragma unroll
  for (int i = 0; i < 21; i++) w[i] = ws[WS_AW + i];

  float a[NLIVE];
  #pragma unroll
  for (int j = 0; j < NLIVE; j++) a[j] = 0.0f;
  if (row < NLIVE) a[row] = 1.0f;
  float L = 0.0f;

  int p1, p2;
  int4 q0 = *(const int4*)(trow + t0);
  int4 q1 = *(const int4*)(trow + t0 + 4);

  int b = 0;
  if (chunk == 0) {
    // steps t = 1..7 (t = 0 is folded into the combine's init)
    p1 = 4; p2 = q0.x;
    int tb[8] = {q0.x, q0.y, q0.z, q0.w, q1.x, q1.y, q1.z, q1.w};
    q0 = *(const int4*)(trow + 8);
    q1 = *(const int4*)(trow + 12);
    #pragma unroll
    for (int u = 1; u < 8; u++) {
      int nt = tb[u];
      hmm_step(a, w, sBt, p1 * 36 + p2 * 6 + nt);
      p1 = p2; p2 = nt;
    }
    renorm(a, L);
    b = 1;
  } else {
    p1 = trow[t0 - 2];
    p2 = trow[t0 - 1];
  }

  for (; b < CLEN / 8; b++) {
    int tb[8] = {q0.x, q0.y, q0.z, q0.w, q1.x, q1.y, q1.z, q1.w};
    if (b < CLEN / 8 - 1) {
      q0 = *(const int4*)(trow + t0 + (b + 1) * 8);
      q1 = *(const int4*)(trow + t0 + (b + 1) * 8 + 4);
    }
    #pragma unroll
    for (int u = 0; u < 8; u++) {
      int nt = tb[u];
      hmm_step(a, w, sBt, p1 * 36 + p2 * 6 + nt);
      p1 = p2; p2 = nt;
    }
    renorm(a, L);
  }

  if (row < NLIVE) {
    float* tb_ = wsT + WS_T + (size_t)((seq * CHUNKS + chunk) * NLIVE + row) * 24;
    *(float4*)(tb_ + 0)  = make_float4(a[0],  a[1],  a[2],  a[3]);
    *(float4*)(tb_ + 4)  = make_float4(a[4],  a[5],  a[6],  a[7]);
    *(float4*)(tb_ + 8)  = make_float4(a[8],  a[9],  a[10], a[11]);
    *(float4*)(tb_ + 12) = make_float4(a[12], a[13], a[14], a[15]);
    *(float4*)(tb_ + 16) = make_float4(a[16], a[17], a[18], a[19]);
    *(float4*)(tb_ + 20) = make_float4(a[20], a[21], a[22], L);
  }
}

// ---------------------------------------------------------------------------
// Combine: one wave per sequence; lane j owns state-column j (j < 23).
// ---------------------------------------------------------------------------
__global__ __launch_bounds__(256)
void combine_kernel(const float* __restrict__ ws, const int* __restrict__ tokens,
                    float* __restrict__ out) {
  const int wave = (blockIdx.x * 256 + threadIdx.x) >> 6;  // = seq
  const int lane = threadIdx.x & 63;
  const int j    = lane;
  const bool act = (j < NLIVE);
  const int jc   = act ? j : 0;

  const int tok0 = tokens[(size_t)wave * TLEN];
  const int flat0 = 168 + tok0;  // tp context (4,4,tok0)

  float v = act ? ws[WS_I + j] * ws[WS_BT + flat0 * 32 + j] : 0.0f;
  float s = v;
  #pragma unroll
  for (int m = 1; m < 32; m <<= 1) s += __shfl_xor(s, m, 32);
  float ll = __logf(s);
  v = act ? v * __fdividef(1.0f, s) : 0.0f;

  const float* T = ws + WS_T + (size_t)wave * CHUNKS * NLIVE * 24;
  for (int c = 0; c < CHUNKS; c++) {
    const float* Tc = T + c * NLIVE * 24;
    float Lj  = act ? Tc[j * 24 + 23] : -3.0e38f;
    float key = (act && v > 0.0f) ? Lj : -3.0e38f;
    float mx = key;
    #pragma unroll
    for (int m = 1; m < 32; m <<= 1) mx = fmaxf(mx, __shfl_xor(mx, m, 32));
    float wgt = (act && v > 0.0f) ? v * __expf(Lj - mx) : 0.0f;

    float nv = 0.0f;
    #pragma unroll
    for (int r = 0; r < NLIVE; r++) {
      float wr = __shfl(wgt, r, 64);
      nv += wr * Tc[r * 24 + jc];
    }
    float nva = act ? nv : 0.0f;
    float s2 = nva;
    #pragma unroll
    for (int m = 1; m < 32; m <<= 1) s2 += __shfl_xor(s2, m, 32);
    ll += mx + __logf(s2);
    v = act ? nv * __fdividef(1.0f, s2) : 0.0f;
  }

  if (lane == 0) out[wave] = ll;
}

// ---------------------------------------------------------------------------
extern "C" void kernel_launch(void* const* d_in, const int* in_sizes, int n_in,
                              void* d_out, int out_size, void* d_ws, size_t ws_size,
                              hipStream_t stream) {
  const float* wT = (const float*)d_in[0];   // transition_kernel (10)
  const float* wE = (const float*)d_in[1];   // emission_kernel (5400)
  const float* wI = (const float*)d_in[2];   // init_kernel (25)
  const int* tokens = (const int*)d_in[3];   // (512, 2048) int32
  float* out = (float*)d_out;                // (512,) float32
  float* ws = (float*)d_ws;                  // needs ~18.2 MB

  setup_kernel<<<1, 256, 0, stream>>>(wT, wE, wI, ws);
  rows_kernel<<<NSEQ * CHUNKS / 8, 256, 0, stream>>>(ws, tokens, ws);
  combine_kernel<<<NSEQ * 64 / 256, 256, 0, stream>>>(ws, tokens, out);
}